// Round 12
// baseline (593.271 us; speedup 1.0000x reference)
//
#include <hip/hip_runtime.h>
#include <hip/hip_fp16.h>
#include <math.h>

#define BS 256
static constexpr int NN = 100000;   // nodes
static constexpr int EE = 1600000;  // directed edges (excl. self loops)
static constexpr int BUCKET_SH = 7;                       // 128 nodes per bucket
static constexpr int NBUCKET = (NN + 127) >> BUCKET_SH;   // 782
static constexpr int NB_PART = 256;                       // partition blocks
static constexpr int CHUNK = EE / NB_PART;                // 6250 (exact)
static constexpr int NP_ = NBUCKET * NB_PART;             // 200192 scan elems
static constexpr int SCAN_ELEMS = 1024;
static constexpr int NPB = (NP_ + SCAN_ELEMS - 1) / SCAN_ELEMS;  // 196

static inline int cdiv(long long a, int b) { return (int)((a + b - 1) / b); }

typedef _Float16 half8 __attribute__((ext_vector_type(8)));
typedef float f32x4 __attribute__((ext_vector_type(4)));

// ---------------- helpers ----------------
template <int ACT>
__device__ __forceinline__ float act_f(float v) {
    if (ACT == 1) return fmaxf(v, 0.0f);
    if (ACT == 2) return tanhf(v);
    return v;
}

__device__ __forceinline__ unsigned short h16(float v) {
    return __half_as_ushort(__float2half(v));
}
__device__ __forceinline__ unsigned pack2h(float a, float b) {
    return (unsigned)h16(a) | ((unsigned)h16(b) << 16);
}
__device__ __forceinline__ float4 cvt4h(uint2 r) {
    float2 fa = __half22float2(*(const __half2*)&r.x);
    float2 fb = __half22float2(*(const __half2*)&r.y);
    return make_float4(fa.x, fa.y, fb.x, fb.y);
}
__device__ __forceinline__ void acc8h(uint4 r, float4& a, float4& b) {
    float2 f0 = __half22float2(*(const __half2*)&r.x);
    float2 f1 = __half22float2(*(const __half2*)&r.y);
    float2 f2 = __half22float2(*(const __half2*)&r.z);
    float2 f3 = __half22float2(*(const __half2*)&r.w);
    a.x += f0.x; a.y += f0.y; a.z += f1.x; a.w += f1.y;
    b.x += f2.x; b.y += f2.y; b.z += f3.x; b.w += f3.y;
}

// OUTM: 0 = fp32, 1 = fp32*dis, 2 = fp16*dis, 3 = fp16 plain
template <int OUTM>
__device__ __forceinline__ void store1(float* out, size_t idx, float v, float dn) {
    if (OUTM == 0) out[idx] = v;
    else if (OUTM == 1) out[idx] = v * dn;
    else if (OUTM == 2) ((unsigned short*)out)[idx] = h16(v * dn);
    else ((unsigned short*)out)[idx] = h16(v);
}

// ---------------- CSR build: contention-free partitioned counting sort ----------------
__global__ __launch_bounds__(256) void k_hist(const int* __restrict__ dst,
                                              int* __restrict__ part_cnt) {
    __shared__ int h[NBUCKET];
    int b = blockIdx.x;
    for (int j = threadIdx.x; j < NBUCKET; j += 256) h[j] = 0;
    __syncthreads();
    int e0 = b * CHUNK;
    for (int k = threadIdx.x; k < CHUNK; k += 256)
        atomicAdd(&h[dst[e0 + k] >> BUCKET_SH], 1);
    __syncthreads();
    for (int j = threadIdx.x; j < NBUCKET; j += 256)
        part_cnt[j * NB_PART + b] = h[j];   // bucket-major for the scan
}

__global__ void k_scanA(const int* __restrict__ in, int* __restrict__ outp,
                        int* __restrict__ bsums) {
    __shared__ int lds[BS];
    int base = blockIdx.x * SCAN_ELEMS;
    int t = threadIdx.x;
    int v[4];
    int s = 0;
#pragma unroll
    for (int j = 0; j < 4; ++j) {
        int idx = base + t * 4 + j;
        v[j] = (idx < NP_) ? in[idx] : 0;
        s += v[j];
    }
    lds[t] = s;
    __syncthreads();
    for (int off = 1; off < BS; off <<= 1) {
        int add = (t >= off) ? lds[t - off] : 0;
        __syncthreads();
        lds[t] += add;
        __syncthreads();
    }
    int run = lds[t] - s;
    if (t == BS - 1) bsums[blockIdx.x] = lds[BS - 1];
#pragma unroll
    for (int j = 0; j < 4; ++j) {
        int idx = base + t * 4 + j;
        if (idx < NP_) outp[idx] = run;
        run += v[j];
    }
}

__global__ void k_scanB(int* __restrict__ bsums) {
    if (threadIdx.x == 0 && blockIdx.x == 0) {
        int acc = 0;
        for (int i = 0; i < NPB; ++i) {
            int t = bsums[i];
            bsums[i] = acc;
            acc += t;
        }
    }
}

__global__ void k_scanC(int* __restrict__ outp, const int* __restrict__ bsums,
                        int* __restrict__ bbase) {
    int i = blockIdx.x * BS + threadIdx.x;
    if (i < NP_) {
        int v = outp[i] + bsums[i / SCAN_ELEMS];
        outp[i] = v;
        if ((i & (NB_PART - 1)) == 0) bbase[i / NB_PART] = v;
    }
    if (i == 0) bbase[NBUCKET] = EE;
}

__global__ __launch_bounds__(256) void k_part(const int* __restrict__ src,
                                              const int* __restrict__ dst,
                                              const int* __restrict__ scan_out,
                                              unsigned* __restrict__ epb) {
    __shared__ int cur[NBUCKET];
    int b = blockIdx.x;
    for (int j = threadIdx.x; j < NBUCKET; j += 256) cur[j] = scan_out[j * NB_PART + b];
    __syncthreads();
    int e0 = b * CHUNK;
    for (int k = threadIdx.x; k < CHUNK; k += 256) {
        int e = e0 + k;
        int d = dst[e];
        int s = src[e];
        int pos = atomicAdd(&cur[d >> BUCKET_SH], 1);
        epb[pos] = ((unsigned)(d & ((1 << BUCKET_SH) - 1)) << 17) | (unsigned)s;
    }
}

__global__ __launch_bounds__(256) void k_fine2(const int* __restrict__ bbase,
                                               const unsigned* __restrict__ epb,
                                               int* __restrict__ eidx,
                                               int* __restrict__ rowptr,
                                               float* __restrict__ dis) {
    __shared__ int hcnt[1 << BUCKET_SH];
    __shared__ int hoff[1 << BUCKET_SH];
    int b = blockIdx.x;
    int n0 = b << BUCKET_SH;
    int nloc = min(1 << BUCKET_SH, NN - n0);
    int t = threadIdx.x;
    if (t < (1 << BUCKET_SH)) hcnt[t] = 0;
    __syncthreads();
    int es = bbase[b], ee = bbase[b + 1];
    for (int k = es + t; k < ee; k += 256) atomicAdd(&hcnt[epb[k] >> 17], 1);
    __syncthreads();
    if (t < (1 << BUCKET_SH)) hoff[t] = hcnt[t];
    __syncthreads();
    for (int off = 1; off < (1 << BUCKET_SH); off <<= 1) {
        int add = (t >= off && t < (1 << BUCKET_SH)) ? hoff[t - off] : 0;
        __syncthreads();
        if (t < (1 << BUCKET_SH)) hoff[t] += add;
        __syncthreads();
    }
    if (t < nloc) {
        int excl = hoff[t] - hcnt[t];
        rowptr[n0 + t] = es + excl;
        dis[n0 + t] = rsqrtf((float)(hcnt[t] + 1));  // + self loop
    }
    __syncthreads();
    if (t < (1 << BUCKET_SH)) hoff[t] = es + hoff[t] - hcnt[t];  // cursors
    __syncthreads();
    for (int k = es + t; k < ee; k += 256) {
        unsigned p = epb[k];
        int pos = atomicAdd(&hoff[p >> 17], 1);
        eidx[pos] = (int)(p & 0x1FFFFu);
    }
    if (b == NBUCKET - 1 && t == 0) rowptr[NN] = EE;
}

// ---------------- gathers ----------------
template <int C, int ACT, bool HASB, bool OUTH>
__global__ void k_gatherw(const unsigned short* __restrict__ g, const int* __restrict__ rowptr,
                          const int* __restrict__ eidx, const float* __restrict__ dis,
                          const float* __restrict__ b, float* __restrict__ out) {
    static_assert(C % 8 == 0, "C%8");
    constexpr int V = C / 8;
    int t = blockIdx.x * BS + threadIdx.x;
    if (t >= NN * V) return;
    int n = t / V, v = t % V;
    const uint4* g4 = (const uint4*)g;
    float4 accA = make_float4(0.f, 0.f, 0.f, 0.f);
    float4 accB = make_float4(0.f, 0.f, 0.f, 0.f);
    acc8h(g4[(size_t)n * V + v], accA, accB);  // self term
    int rs = rowptr[n], re = rowptr[n + 1];
    int k = rs;
    for (; k + 4 <= re; k += 4) {
        int s0 = eidx[k + 0], s1 = eidx[k + 1], s2 = eidx[k + 2], s3 = eidx[k + 3];
        uint4 r0 = g4[(size_t)s0 * V + v];
        uint4 r1 = g4[(size_t)s1 * V + v];
        uint4 r2 = g4[(size_t)s2 * V + v];
        uint4 r3 = g4[(size_t)s3 * V + v];
        acc8h(r0, accA, accB);
        acc8h(r1, accA, accB);
        acc8h(r2, accA, accB);
        acc8h(r3, accA, accB);
    }
    for (; k < re; ++k) {
        acc8h(g4[(size_t)eidx[k] * V + v], accA, accB);
    }
    float dn = dis[n];
    accA.x *= dn; accA.y *= dn; accA.z *= dn; accA.w *= dn;
    accB.x *= dn; accB.y *= dn; accB.z *= dn; accB.w *= dn;
    if (HASB) {
        float4 b0 = ((const float4*)b)[v * 2 + 0];
        float4 b1 = ((const float4*)b)[v * 2 + 1];
        accA.x += b0.x; accA.y += b0.y; accA.z += b0.z; accA.w += b0.w;
        accB.x += b1.x; accB.y += b1.y; accB.z += b1.z; accB.w += b1.w;
    }
    accA.x = act_f<ACT>(accA.x); accA.y = act_f<ACT>(accA.y);
    accA.z = act_f<ACT>(accA.z); accA.w = act_f<ACT>(accA.w);
    accB.x = act_f<ACT>(accB.x); accB.y = act_f<ACT>(accB.y);
    accB.z = act_f<ACT>(accB.z); accB.w = act_f<ACT>(accB.w);
    if (OUTH) {
        uint4 u;
        u.x = pack2h(accA.x, accA.y);
        u.y = pack2h(accA.z, accA.w);
        u.z = pack2h(accB.x, accB.y);
        u.w = pack2h(accB.z, accB.w);
        ((uint4*)out)[(size_t)n * V + v] = u;
    } else {
        float4* op = (float4*)out + (size_t)n * (C / 4) + v * 2;
        op[0] = accA;
        op[1] = accB;
    }
}

template <int C, int ACT, bool HASB, bool OUTH>
__global__ void k_gatherh(const unsigned short* __restrict__ g, const int* __restrict__ rowptr,
                          const int* __restrict__ eidx, const float* __restrict__ dis,
                          const float* __restrict__ b, float* __restrict__ out) {
    static_assert(C % 4 == 0, "C%4");
    constexpr int V = C / 4;
    int t = blockIdx.x * BS + threadIdx.x;
    if (t >= NN * V) return;
    int n = t / V, v = t % V;
    const uint2* g2 = (const uint2*)g;
    float4 acc = cvt4h(g2[(size_t)n * V + v]);  // self term
    int rs = rowptr[n], re = rowptr[n + 1];
    int k = rs;
    for (; k + 4 <= re; k += 4) {
        int s0 = eidx[k + 0], s1 = eidx[k + 1], s2 = eidx[k + 2], s3 = eidx[k + 3];
        uint2 r0 = g2[(size_t)s0 * V + v];
        uint2 r1 = g2[(size_t)s1 * V + v];
        uint2 r2 = g2[(size_t)s2 * V + v];
        uint2 r3 = g2[(size_t)s3 * V + v];
        float4 h0 = cvt4h(r0), h1 = cvt4h(r1), h2 = cvt4h(r2), h3 = cvt4h(r3);
        acc.x += (h0.x + h1.x) + (h2.x + h3.x);
        acc.y += (h0.y + h1.y) + (h2.y + h3.y);
        acc.z += (h0.z + h1.z) + (h2.z + h3.z);
        acc.w += (h0.w + h1.w) + (h2.w + h3.w);
    }
    for (; k < re; ++k) {
        float4 hv = cvt4h(g2[(size_t)eidx[k] * V + v]);
        acc.x += hv.x; acc.y += hv.y; acc.z += hv.z; acc.w += hv.w;
    }
    float dn = dis[n];
    acc.x *= dn; acc.y *= dn; acc.z *= dn; acc.w *= dn;
    if (HASB) {
        float4 bb = ((const float4*)b)[v];
        acc.x += bb.x; acc.y += bb.y; acc.z += bb.z; acc.w += bb.w;
    }
    acc.x = act_f<ACT>(acc.x);
    acc.y = act_f<ACT>(acc.y);
    acc.z = act_f<ACT>(acc.z);
    acc.w = act_f<ACT>(acc.w);
    if (OUTH) {
        uint2 u;
        u.x = pack2h(acc.x, acc.y);
        u.y = pack2h(acc.z, acc.w);
        ((uint2*)out)[(size_t)n * V + v] = u;
    } else {
        ((float4*)out)[(size_t)n * V + v] = acc;
    }
}

template <int ACT, bool HASB>
__global__ void k_gather3d(const float* __restrict__ g, const int* __restrict__ rowptr,
                           const int* __restrict__ eidx, const float* __restrict__ dis,
                           const float* __restrict__ b, float* __restrict__ out) {
    int n = blockIdx.x * BS + threadIdx.x;
    if (n >= NN) return;
    const float* gp = g + (size_t)n * 3;
    float a0 = gp[0], a1 = gp[1], a2 = gp[2];
    int rs = rowptr[n], re = rowptr[n + 1];
    int k = rs;
    for (; k + 4 <= re; k += 4) {
        const float* q0 = g + (size_t)eidx[k + 0] * 3;
        const float* q1 = g + (size_t)eidx[k + 1] * 3;
        const float* q2 = g + (size_t)eidx[k + 2] * 3;
        const float* q3 = g + (size_t)eidx[k + 3] * 3;
        float b00 = q0[0], b01 = q0[1], b02 = q0[2];
        float b10 = q1[0], b11 = q1[1], b12 = q1[2];
        float b20 = q2[0], b21 = q2[1], b22 = q2[2];
        float b30 = q3[0], b31 = q3[1], b32 = q3[2];
        a0 += (b00 + b10) + (b20 + b30);
        a1 += (b01 + b11) + (b21 + b31);
        a2 += (b02 + b12) + (b22 + b32);
    }
    for (; k < re; ++k) {
        const float* gq = g + (size_t)eidx[k] * 3;
        a0 += gq[0]; a1 += gq[1]; a2 += gq[2];
    }
    float dn = dis[n];
    a0 *= dn; a1 *= dn; a2 *= dn;
    if (HASB) { a0 += b[0]; a1 += b[1]; a2 += b[2]; }
    float* op = out + (size_t)n * 3;
    op[0] = act_f<ACT>(a0);
    op[1] = act_f<ACT>(a1);
    op[2] = act_f<ACT>(a2);
}

__global__ void k_scale3(const float* __restrict__ x, const float* __restrict__ dis,
                         float* __restrict__ g) {
    int i = blockIdx.x * BS + threadIdx.x;
    if (i < NN * 3) g[i] = x[i] * dis[i / 3];
}

// ---------------- fused latent stack ----------------
__global__ __launch_bounds__(256) void k_latent(const unsigned short* __restrict__ in20,
                                                const float* __restrict__ el1_w, const float* __restrict__ el1_b,
                                                const float* __restrict__ el2_w, const float* __restrict__ el2_b,
                                                const float* __restrict__ dl1_w, const float* __restrict__ dl1_b,
                                                const float* __restrict__ dl2_w, const float* __restrict__ dl2_b,
                                                const float* __restrict__ dis,
                                                unsigned short* __restrict__ G) {
    __shared__ float w1[200], b1[10], w2[30], b2[3], w3[30], b3[10], w4[200], b4[20];
    int t = threadIdx.x;
    if (t < 200) w1[t] = el1_w[t];
    if (t < 10) b1[t] = el1_b[t];
    if (t < 30) w2[t] = el2_w[t];
    if (t < 3) b2[t] = el2_b[t];
    if (t < 30) w3[t] = dl1_w[t];
    if (t < 10) b3[t] = dl1_b[t];
    if (t < 200) w4[t] = dl2_w[t];
    if (t < 20) b4[t] = dl2_b[t];
    __syncthreads();
    int n = blockIdx.x * 256 + t;
    if (n >= NN) return;
    float h0[20];
    const uint2* ip = (const uint2*)in20 + (size_t)n * 5;
#pragma unroll
    for (int v = 0; v < 5; ++v) {
        float4 f = cvt4h(ip[v]);
        h0[v * 4 + 0] = f.x; h0[v * 4 + 1] = f.y;
        h0[v * 4 + 2] = f.z; h0[v * 4 + 3] = f.w;
    }
    float a1[10];
#pragma unroll
    for (int j = 0; j < 10; ++j) {
        float s = b1[j];
#pragma unroll
        for (int i = 0; i < 20; ++i) s = fmaf(h0[i], w1[i * 10 + j], s);
        a1[j] = fmaxf(s, 0.0f);
    }
    float a2[3];
#pragma unroll
    for (int j = 0; j < 3; ++j) {
        float s = b2[j];
#pragma unroll
        for (int i = 0; i < 10; ++i) s = fmaf(a1[i], w2[i * 3 + j], s);
        a2[j] = s;
    }
    float a3[10];
#pragma unroll
    for (int j = 0; j < 10; ++j) {
        float s = b3[j];
#pragma unroll
        for (int i = 0; i < 3; ++i) s = fmaf(a2[i], w3[i * 10 + j], s);
        a3[j] = fmaxf(s, 0.0f);
    }
    float dn = dis[n];
    uint2* gp = (uint2*)G + (size_t)n * 5;
#pragma unroll
    for (int v = 0; v < 5; ++v) {
        float o[4];
#pragma unroll
        for (int q = 0; q < 4; ++q) {
            int j = v * 4 + q;
            float s = b4[j];
#pragma unroll
            for (int i = 0; i < 10; ++i) s = fmaf(a3[i], w4[i * 20 + j], s);
            o[q] = fmaxf(s, 0.0f) * dn;
        }
        uint2 u;
        u.x = pack2h(o[0], o[1]);
        u.y = pack2h(o[2], o[3]);
        gp[v] = u;
    }
}

// ---------------- MFMA GEMM: X [NN][K] fp16 -> out [NN][N] fp16 ----------------
// block = 256 threads = 4 waves x 16 rows. W staged fp16 swizzled [k/8][n][k%8].
// A/B frags: outer idx = lane&15, k = quad*8+j (same mapping both sides ->
// k-permutation cancels). C/D: col=lane&15, row=quad*4+reg (HW-verified).
template <int K, int N, int ACT, bool HASB, int OUTM>
__global__ __launch_bounds__(256) void k_mm_mfma(const unsigned short* __restrict__ x,
                                                 const float* __restrict__ w,
                                                 const float* __restrict__ bias,
                                                 unsigned short* __restrict__ out,
                                                 const float* __restrict__ dis) {
    constexpr int KP = (K + 31) & ~31;   // K padded to 32
    constexpr int NT = (N + 15) / 16;    // 16-col tiles
    constexpr int NPAD = NT * 16;
    constexpr int KC = KP / 32;
    constexpr int SP = KP + 8;           // A row stride in halves (+16B pad)
    __shared__ _Float16 Al[64 * SP];
    __shared__ _Float16 Wl[(KP / 8) * NPAD * 8];
    const int tid = threadIdx.x;
    const int n0 = blockIdx.x * 64;

    // stage A (bit-copy fp16, zero-pad K tail and OOB rows)
    {
        constexpr int K4 = KP / 4;
        const uint2* x2 = (const uint2*)x;  // 4 halves per uint2
        for (int i = tid; i < 64 * K4; i += 256) {
            int r = i / K4, k4 = i % K4;
            uint2 v = make_uint2(0u, 0u);
            int row = n0 + r;
            if (row < NN && k4 * 4 < K) v = x2[(size_t)row * (K / 4) + k4];
            *(uint2*)&Al[r * SP + k4 * 4] = v;
        }
    }
    // stage W swizzled: Wl[(k>>3)*NPAD*8 + n*8 + (k&7)]
    for (int i = tid; i < KP * NPAD; i += 256) {
        int k = i / NPAD, n = i % NPAD;
        float v = (k < K && n < N) ? w[k * N + n] : 0.0f;
        Wl[(k >> 3) * NPAD * 8 + n * 8 + (k & 7)] = (_Float16)v;
    }
    __syncthreads();

    const int wave = tid >> 6;
    const int lane = tid & 63;
    const int lm = lane & 15;
    const int quad = lane >> 4;

    f32x4 acc[NT];
#pragma unroll
    for (int t = 0; t < NT; ++t) acc[t] = (f32x4){0.f, 0.f, 0.f, 0.f};

    const int arow = wave * 16 + lm;
#pragma unroll
    for (int kc = 0; kc < KC; ++kc) {
        half8 a = *(const half8*)&Al[arow * SP + kc * 32 + quad * 8];
#pragma unroll
        for (int t = 0; t < NT; ++t) {
            half8 bf = *(const half8*)&Wl[(kc * 4 + quad) * NPAD * 8 + (t * 16 + lm) * 8];
            acc[t] = __builtin_amdgcn_mfma_f32_16x16x32_f16(a, bf, acc[t], 0, 0, 0);
        }
    }
#pragma unroll
    for (int t = 0; t < NT; ++t) {
        int col = t * 16 + lm;
        if (col < N) {
            float bb = HASB ? bias[col] : 0.0f;
#pragma unroll
            for (int r = 0; r < 4; ++r) {
                int row = n0 + wave * 16 + quad * 4 + r;
                if (row < NN) {
                    float v = act_f<ACT>(acc[t][r] + bb);
                    if (OUTM == 2) v *= dis[row];
                    out[(size_t)row * N + col] = h16(v);
                }
            }
        }
    }
}

// ---------------- small-CIN matmul, vectorized output (fp32 or fp16) ----------------
template <int CIN, int COUT, int ACT, int OUTM>
__global__ void k_mm_rowbcast(const float* __restrict__ x, const float* __restrict__ w,
                              const float* __restrict__ b, float* __restrict__ out) {
    static_assert(COUT % 4 == 0, "c4");
    constexpr int COUT4 = COUT / 4;
    int i = blockIdx.x * BS + threadIdx.x;
    if (i >= NN * COUT4) return;
    int n = i / COUT4, c4 = i % COUT4;
    const float4* w4 = (const float4*)w;
    float4 acc = ((const float4*)b)[c4];
    const float* xr = x + (size_t)n * CIN;
#pragma unroll
    for (int ci = 0; ci < CIN; ++ci) {
        float xv = xr[ci];
        float4 wv = w4[ci * COUT4 + c4];
        acc.x = fmaf(xv, wv.x, acc.x);
        acc.y = fmaf(xv, wv.y, acc.y);
        acc.z = fmaf(xv, wv.z, acc.z);
        acc.w = fmaf(xv, wv.w, acc.w);
    }
    acc.x = act_f<ACT>(acc.x); acc.y = act_f<ACT>(acc.y);
    acc.z = act_f<ACT>(acc.z); acc.w = act_f<ACT>(acc.w);
    if (OUTM == 3) {
        uint2 u;
        u.x = pack2h(acc.x, acc.y);
        u.y = pack2h(acc.z, acc.w);
        ((uint2*)out)[(size_t)n * COUT4 + c4] = u;
    } else {
        ((float4*)out)[(size_t)n * COUT4 + c4] = acc;
    }
}

// ---------------- mm_vec4: TM=8 rows x 4 cols per thread (INH: fp16 input) ----------------
template <int CIN, int COUT, int ACT, bool HASB, int OUTM, bool INH>
__global__ void k_mm_vec4(const float* __restrict__ x, const float* __restrict__ w,
                          const float* __restrict__ b, float* __restrict__ out,
                          const float* __restrict__ dis) {
    static_assert(CIN % 4 == 0 && COUT % 4 == 0, "align");
    constexpr int TM = 8;
    constexpr int CIN4 = CIN / 4;
    constexpr int COUT4 = COUT / 4;
    constexpr int RG = NN / TM;
    int i = blockIdx.x * BS + threadIdx.x;
    if (i >= RG * COUT4) return;
    int c4 = i % COUT4;
    int n0 = (i / COUT4) * TM;
    const float4* x4 = (const float4*)x;
    const uint2* xh = (const uint2*)x;
    const float4* w4 = (const float4*)w;
    float4 acc[TM];
    float4 bb = HASB ? ((const float4*)b)[c4] : make_float4(0.f, 0.f, 0.f, 0.f);
#pragma unroll
    for (int r = 0; r < TM; ++r) acc[r] = bb;
    for (int k4 = 0; k4 < CIN4; ++k4) {
        float4 wv[4];
#pragma unroll
        for (int j = 0; j < 4; ++j) wv[j] = w4[(size_t)(4 * k4 + j) * COUT4 + c4];
#pragma unroll
        for (int r = 0; r < TM; ++r) {
            float4 xv;
            if (INH) xv = cvt4h(xh[(size_t)(n0 + r) * CIN4 + k4]);
            else xv = x4[(size_t)(n0 + r) * CIN4 + k4];
            acc[r].x = fmaf(xv.x, wv[0].x, fmaf(xv.y, wv[1].x, fmaf(xv.z, wv[2].x, fmaf(xv.w, wv[3].x, acc[r].x))));
            acc[r].y = fmaf(xv.x, wv[0].y, fmaf(xv.y, wv[1].y, fmaf(xv.z, wv[2].y, fmaf(xv.w, wv[3].y, acc[r].y))));
            acc[r].z = fmaf(xv.x, wv[0].z, fmaf(xv.y, wv[1].z, fmaf(xv.z, wv[2].z, fmaf(xv.w, wv[3].z, acc[r].z))));
            acc[r].w = fmaf(xv.x, wv[0].w, fmaf(xv.y, wv[1].w, fmaf(xv.z, wv[2].w, fmaf(xv.w, wv[3].w, acc[r].w))));
        }
    }
#pragma unroll
    for (int r = 0; r < TM; ++r) {
        float vx = act_f<ACT>(acc[r].x), vy = act_f<ACT>(acc[r].y);
        float vz = act_f<ACT>(acc[r].z), vw = act_f<ACT>(acc[r].w);
        size_t gi = (size_t)(n0 + r) * COUT4 + c4;
        if (OUTM == 2) {
            float dn = dis[n0 + r];
            uint2 u;
            u.x = pack2h(vx * dn, vy * dn);
            u.y = pack2h(vz * dn, vw * dn);
            ((uint2*)out)[gi] = u;
        } else if (OUTM == 1) {
            float dn = dis[n0 + r];
            ((float4*)out)[gi] = make_float4(vx * dn, vy * dn, vz * dn, vw * dn);
        } else {
            ((float4*)out)[gi] = make_float4(vx, vy, vz, vw);
        }
    }
}

// ---------------- vec matmul (odd COUT; INH = fp16 input) ----------------
template <int CIN, int COUT, int ACT, bool HASB, int OUTM, bool INH>
__global__ void k_mm_vec(const float* __restrict__ x, const float* __restrict__ w,
                         const float* __restrict__ b, float* __restrict__ out,
                         const float* __restrict__ dis) {
    static_assert(CIN % 4 == 0, "CIN%4");
    constexpr int TM = 8;
    constexpr int CIN4 = CIN / 4;
    constexpr int RG = NN / TM;
    int i = blockIdx.x * BS + threadIdx.x;
    if (i >= RG * COUT) return;
    int c = i % COUT;
    int n0 = (i / COUT) * TM;
    float acc[TM];
    float bb = HASB ? b[c] : 0.0f;
#pragma unroll
    for (int r = 0; r < TM; ++r) acc[r] = bb;
    const float4* x4 = (const float4*)x;
    const uint2* xh = (const uint2*)x;
    for (int k = 0; k < CIN4; ++k) {
        float w0 = w[(4 * k + 0) * COUT + c];
        float w1 = w[(4 * k + 1) * COUT + c];
        float w2 = w[(4 * k + 2) * COUT + c];
        float w3 = w[(4 * k + 3) * COUT + c];
#pragma unroll
        for (int r = 0; r < TM; ++r) {
            float4 xv;
            if (INH) xv = cvt4h(xh[(size_t)(n0 + r) * CIN4 + k]);
            else xv = x4[(size_t)(n0 + r) * CIN4 + k];
            acc[r] = fmaf(xv.x, w0, fmaf(xv.y, w1, fmaf(xv.z, w2, fmaf(xv.w, w3, acc[r]))));
        }
    }
#pragma unroll
    for (int r = 0; r < TM; ++r) {
        int row = n0 + r;
        float dn = (OUTM == 1 || OUTM == 2) ? dis[row] : 0.0f;
        store1<OUTM>(out, (size_t)row * COUT + c, act_f<ACT>(acc[r]), dn);
    }
}

extern "C" void kernel_launch(void* const* d_in, const int* in_sizes, int n_in,
                              void* d_out, int out_size, void* d_ws, size_t ws_size,
                              hipStream_t stream) {
    const float* x = (const float*)d_in[0];
    const int* ei = (const int*)d_in[1];
    const int* src = ei;
    const int* dst = ei + EE;
    const float* eg1_w = (const float*)d_in[2];  const float* eg1_b = (const float*)d_in[3];
    const float* eg2_w = (const float*)d_in[4];  const float* eg2_b = (const float*)d_in[5];
    const float* eg3_w = (const float*)d_in[6];  const float* eg3_b = (const float*)d_in[7];
    const float* eg4_w = (const float*)d_in[8];  const float* eg4_b = (const float*)d_in[9];
    const float* el1_w = (const float*)d_in[10]; const float* el1_b = (const float*)d_in[11];
    const float* el2_w = (const float*)d_in[12]; const float* el2_b = (const float*)d_in[13];
    const float* dl1_w = (const float*)d_in[14]; const float* dl1_b = (const float*)d_in[15];
    const float* dl2_w = (const float*)d_in[16]; const float* dl2_b = (const float*)d_in[17];
    const float* dg1_w = (const float*)d_in[18]; const float* dg1_b = (const float*)d_in[19];
    const float* dg2_w = (const float*)d_in[20]; const float* dg2_b = (const float*)d_in[21];
    const float* dg3_w = (const float*)d_in[22]; const float* dg3_b = (const float*)d_in[23];
    const float* dg4_w = (const float*)d_in[24]; const float* dg4_b = (const float*)d_in[25];
    float* out = (float*)d_out;

    char* ws = (char*)d_ws;
    size_t off = 0;
    auto alloc = [&](size_t bytes) {
        void* p = ws + off;
        off += (bytes + 15) & ~(size_t)15;
        return p;
    };
    int* part_cnt = (int*)alloc(sizeof(int) * NP_);
    int* scan_out = (int*)alloc(sizeof(int) * NP_);
    int* bsums    = (int*)alloc(sizeof(int) * NPB);
    int* bbase    = (int*)alloc(sizeof(int) * (NBUCKET + 1));
    int* rowptr   = (int*)alloc(sizeof(int) * (NN + 1));
    float* dis    = (float*)alloc(sizeof(float) * NN);
    int* eidx     = (int*)alloc(sizeof(int) * EE);
    unsigned* epb = (unsigned*)alloc(sizeof(unsigned) * EE);
    unsigned short* G = (unsigned short*)alloc(sizeof(unsigned short) * 80 * (size_t)NN);
    float* bufA = (float*)alloc(sizeof(float) * 160 * (size_t)NN);
    float* bufB = (float*)alloc(sizeof(float) * 160 * (size_t)NN);

    // ---- CSR build (no global atomics anywhere) ----
    k_hist<<<NB_PART, 256, 0, stream>>>(dst, part_cnt);
    k_scanA<<<NPB, BS, 0, stream>>>(part_cnt, scan_out, bsums);
    k_scanB<<<1, 64, 0, stream>>>(bsums);
    k_scanC<<<cdiv(NP_, BS), BS, 0, stream>>>(scan_out, bsums, bbase);
    k_part<<<NB_PART, 256, 0, stream>>>(src, dst, scan_out, epb);
    k_fine2<<<NBUCKET, 256, 0, stream>>>(bbase, epb, eidx, rowptr, dis);

    // ---- eg1 (3->160): AGG-first; output fp16 (plain, row-major) into bufB ----
    k_scale3<<<cdiv(3LL * NN, BS), BS, 0, stream>>>(x, dis, bufB);
    k_gather3d<0, false><<<cdiv(NN, BS), BS, 0, stream>>>(bufB, rowptr, eidx, dis, nullptr, bufA);
    k_mm_rowbcast<3, 160, 1, 3><<<cdiv(NN * 40LL, BS), BS, 0, stream>>>(bufA, eg1_w, eg1_b, bufB);

    // ---- eg2 (160->80): MFMA mm (fp16 in) -> fp16*dis G; wide gather -> fp16 out ----
    k_mm_mfma<160, 80, 0, false, 2><<<cdiv(NN, 64), 256, 0, stream>>>(
        (const unsigned short*)bufB, eg2_w, nullptr, G, dis);
    k_gatherw<80, 1, true, true><<<cdiv(NN * 10LL, BS), BS, 0, stream>>>(G, rowptr, eidx, dis, eg2_b, bufA);

    // ---- eg3 (80->40): MFMA mm -> fp16*dis G; wide gather -> fp16 out ----
    k_mm_mfma<80, 40, 0, false, 2><<<cdiv(NN, 64), 256, 0, stream>>>(
        (const unsigned short*)bufA, eg3_w, nullptr, G, dis);
    k_gatherw<40, 1, true, true><<<cdiv(NN * 5LL, BS), BS, 0, stream>>>(G, rowptr, eidx, dis, eg3_b, bufB);

    // ---- eg4 (40->20): mm (fp16 in) -> fp16*dis G; gather -> fp16 out ----
    k_mm_vec4<40, 20, 0, false, 2, true><<<cdiv((NN / 8) * 5LL, BS), BS, 0, stream>>>(
        bufB, eg4_w, nullptr, (float*)G, dis);
    k_gatherh<20, 1, true, true><<<cdiv(NN * 5LL, BS), BS, 0, stream>>>(G, rowptr, eidx, dis, eg4_b, bufA);

    // ---- fused latent stack (20->10->3->10->20), writes dis-scaled fp16 G for dg1 ----
    k_latent<<<cdiv(NN, 256), 256, 0, stream>>>((const unsigned short*)bufA,
        el1_w, el1_b, el2_w, el2_b, dl1_w, dl1_b, dl2_w, dl2_b, dis, G);

    // ---- dg1 (20->40): gather -> fp16, mm (fp16 in) -> fp16*dis G ----
    k_gatherh<20, 0, false, true><<<cdiv(NN * 5LL, BS), BS, 0, stream>>>(G, rowptr, eidx, dis, nullptr, bufA);
    k_mm_vec4<20, 40, 1, true, 2, true><<<cdiv((NN / 8) * 10LL, BS), BS, 0, stream>>>(
        bufA, dg1_w, dg1_b, (float*)G, dis);

    // ---- dg2 (40->80): wide gather -> fp16, MFMA mm (relu+bias) -> fp16*dis G ----
    k_gatherw<40, 0, false, true><<<cdiv(NN * 5LL, BS), BS, 0, stream>>>(G, rowptr, eidx, dis, nullptr, bufB);
    k_mm_mfma<40, 80, 1, true, 2><<<cdiv(NN, 64), 256, 0, stream>>>(
        (const unsigned short*)bufB, dg2_w, dg2_b, G, dis);

    // ---- dg3 (80->160): wide gather -> fp16, MFMA mm (relu+bias) -> fp16 plain ----
    k_gatherw<80, 0, false, true><<<cdiv(NN * 10LL, BS), BS, 0, stream>>>(G, rowptr, eidx, dis, nullptr, bufA);
    k_mm_mfma<80, 160, 1, true, 3><<<cdiv(NN, 64), 256, 0, stream>>>(
        (const unsigned short*)bufA, dg3_w, dg3_b, (unsigned short*)bufB, nullptr);

    // ---- dg4 (160->3): mm (fp16 in) writes dis-scaled fp32 g; tanh in gather ----
    k_mm_vec<160, 3, 0, false, 1, true><<<cdiv((NN / 8) * 3LL, BS), BS, 0, stream>>>(bufB, dg4_w, nullptr, bufA, dis);
    k_gather3d<2, true><<<cdiv(NN, BS), BS, 0, stream>>>(bufA, rowptr, eidx, dis, dg4_b, out);
}

// Round 13
// 527.428 us; speedup vs baseline: 1.1248x; 1.1248x over previous
//
#include <hip/hip_runtime.h>
#include <hip/hip_fp16.h>
#include <math.h>

#define BS 256
static constexpr int NN = 100000;   // nodes
static constexpr int EE = 1600000;  // directed edges (excl. self loops)
static constexpr int BUCKET_SH = 7;                       // 128 nodes per bucket
static constexpr int NBUCKET = (NN + 127) >> BUCKET_SH;   // 782
static constexpr int NB_PART = 256;                       // partition blocks
static constexpr int CHUNK = EE / NB_PART;                // 6250 (exact)
static constexpr int NP_ = NBUCKET * NB_PART;             // 200192 scan elems
static constexpr int SCAN_ELEMS = 1024;
static constexpr int NPB = (NP_ + SCAN_ELEMS - 1) / SCAN_ELEMS;  // 196

static inline int cdiv(long long a, int b) { return (int)((a + b - 1) / b); }

typedef _Float16 half8 __attribute__((ext_vector_type(8)));
typedef float f32x4 __attribute__((ext_vector_type(4)));

// ---------------- helpers ----------------
template <int ACT>
__device__ __forceinline__ float act_f(float v) {
    if (ACT == 1) return fmaxf(v, 0.0f);
    if (ACT == 2) return tanhf(v);
    return v;
}

__device__ __forceinline__ unsigned short h16(float v) {
    return __half_as_ushort(__float2half(v));
}
__device__ __forceinline__ unsigned pack2h(float a, float b) {
    return (unsigned)h16(a) | ((unsigned)h16(b) << 16);
}
__device__ __forceinline__ float4 cvt4h(uint2 r) {
    float2 fa = __half22float2(*(const __half2*)&r.x);
    float2 fb = __half22float2(*(const __half2*)&r.y);
    return make_float4(fa.x, fa.y, fb.x, fb.y);
}
__device__ __forceinline__ void acc8h(uint4 r, float4& a, float4& b) {
    float2 f0 = __half22float2(*(const __half2*)&r.x);
    float2 f1 = __half22float2(*(const __half2*)&r.y);
    float2 f2 = __half22float2(*(const __half2*)&r.z);
    float2 f3 = __half22float2(*(const __half2*)&r.w);
    a.x += f0.x; a.y += f0.y; a.z += f1.x; a.w += f1.y;
    b.x += f2.x; b.y += f2.y; b.z += f3.x; b.w += f3.y;
}

// OUTM: 0 = fp32, 1 = fp32*dis, 2 = fp16*dis, 3 = fp16 plain
template <int OUTM>
__device__ __forceinline__ void store1(float* out, size_t idx, float v, float dn) {
    if (OUTM == 0) out[idx] = v;
    else if (OUTM == 1) out[idx] = v * dn;
    else if (OUTM == 2) ((unsigned short*)out)[idx] = h16(v * dn);
    else ((unsigned short*)out)[idx] = h16(v);
}

// ---------------- CSR build: contention-free partitioned counting sort ----------------
__global__ __launch_bounds__(256) void k_hist(const int* __restrict__ dst,
                                              int* __restrict__ part_cnt) {
    __shared__ int h[NBUCKET];
    int b = blockIdx.x;
    for (int j = threadIdx.x; j < NBUCKET; j += 256) h[j] = 0;
    __syncthreads();
    int e0 = b * CHUNK;
    for (int k = threadIdx.x; k < CHUNK; k += 256)
        atomicAdd(&h[dst[e0 + k] >> BUCKET_SH], 1);
    __syncthreads();
    for (int j = threadIdx.x; j < NBUCKET; j += 256)
        part_cnt[j * NB_PART + b] = h[j];   // bucket-major for the scan
}

__global__ void k_scanA(const int* __restrict__ in, int* __restrict__ outp,
                        int* __restrict__ bsums) {
    __shared__ int lds[BS];
    int base = blockIdx.x * SCAN_ELEMS;
    int t = threadIdx.x;
    int v[4];
    int s = 0;
#pragma unroll
    for (int j = 0; j < 4; ++j) {
        int idx = base + t * 4 + j;
        v[j] = (idx < NP_) ? in[idx] : 0;
        s += v[j];
    }
    lds[t] = s;
    __syncthreads();
    for (int off = 1; off < BS; off <<= 1) {
        int add = (t >= off) ? lds[t - off] : 0;
        __syncthreads();
        lds[t] += add;
        __syncthreads();
    }
    int run = lds[t] - s;
    if (t == BS - 1) bsums[blockIdx.x] = lds[BS - 1];
#pragma unroll
    for (int j = 0; j < 4; ++j) {
        int idx = base + t * 4 + j;
        if (idx < NP_) outp[idx] = run;
        run += v[j];
    }
}

__global__ void k_scanB(int* __restrict__ bsums) {
    if (threadIdx.x == 0 && blockIdx.x == 0) {
        int acc = 0;
        for (int i = 0; i < NPB; ++i) {
            int t = bsums[i];
            bsums[i] = acc;
            acc += t;
        }
    }
}

__global__ void k_scanC(int* __restrict__ outp, const int* __restrict__ bsums,
                        int* __restrict__ bbase) {
    int i = blockIdx.x * BS + threadIdx.x;
    if (i < NP_) {
        int v = outp[i] + bsums[i / SCAN_ELEMS];
        outp[i] = v;
        if ((i & (NB_PART - 1)) == 0) bbase[i / NB_PART] = v;
    }
    if (i == 0) bbase[NBUCKET] = EE;
}

__global__ __launch_bounds__(256) void k_part(const int* __restrict__ src,
                                              const int* __restrict__ dst,
                                              const int* __restrict__ scan_out,
                                              unsigned* __restrict__ epb) {
    __shared__ int cur[NBUCKET];
    int b = blockIdx.x;
    for (int j = threadIdx.x; j < NBUCKET; j += 256) cur[j] = scan_out[j * NB_PART + b];
    __syncthreads();
    int e0 = b * CHUNK;
    for (int k = threadIdx.x; k < CHUNK; k += 256) {
        int e = e0 + k;
        int d = dst[e];
        int s = src[e];
        int pos = atomicAdd(&cur[d >> BUCKET_SH], 1);
        epb[pos] = ((unsigned)(d & ((1 << BUCKET_SH) - 1)) << 17) | (unsigned)s;
    }
}

__global__ __launch_bounds__(256) void k_fine2(const int* __restrict__ bbase,
                                               const unsigned* __restrict__ epb,
                                               int* __restrict__ eidx,
                                               int* __restrict__ rowptr,
                                               float* __restrict__ dis) {
    __shared__ int hcnt[1 << BUCKET_SH];
    __shared__ int hoff[1 << BUCKET_SH];
    int b = blockIdx.x;
    int n0 = b << BUCKET_SH;
    int nloc = min(1 << BUCKET_SH, NN - n0);
    int t = threadIdx.x;
    if (t < (1 << BUCKET_SH)) hcnt[t] = 0;
    __syncthreads();
    int es = bbase[b], ee = bbase[b + 1];
    for (int k = es + t; k < ee; k += 256) atomicAdd(&hcnt[epb[k] >> 17], 1);
    __syncthreads();
    if (t < (1 << BUCKET_SH)) hoff[t] = hcnt[t];
    __syncthreads();
    for (int off = 1; off < (1 << BUCKET_SH); off <<= 1) {
        int add = (t >= off && t < (1 << BUCKET_SH)) ? hoff[t - off] : 0;
        __syncthreads();
        if (t < (1 << BUCKET_SH)) hoff[t] += add;
        __syncthreads();
    }
    if (t < nloc) {
        int excl = hoff[t] - hcnt[t];
        rowptr[n0 + t] = es + excl;
        dis[n0 + t] = rsqrtf((float)(hcnt[t] + 1));  // + self loop
    }
    __syncthreads();
    if (t < (1 << BUCKET_SH)) hoff[t] = es + hoff[t] - hcnt[t];  // cursors
    __syncthreads();
    for (int k = es + t; k < ee; k += 256) {
        unsigned p = epb[k];
        int pos = atomicAdd(&hoff[p >> 17], 1);
        eidx[pos] = (int)(p & 0x1FFFFu);
    }
    if (b == NBUCKET - 1 && t == 0) rowptr[NN] = EE;
}

// ---------------- gathers ----------------
template <int C, int ACT, bool HASB, bool OUTH>
__global__ void k_gatherw(const unsigned short* __restrict__ g, const int* __restrict__ rowptr,
                          const int* __restrict__ eidx, const float* __restrict__ dis,
                          const float* __restrict__ b, float* __restrict__ out) {
    static_assert(C % 8 == 0, "C%8");
    constexpr int V = C / 8;
    int t = blockIdx.x * BS + threadIdx.x;
    if (t >= NN * V) return;
    int n = t / V, v = t % V;
    const uint4* g4 = (const uint4*)g;
    float4 accA = make_float4(0.f, 0.f, 0.f, 0.f);
    float4 accB = make_float4(0.f, 0.f, 0.f, 0.f);
    acc8h(g4[(size_t)n * V + v], accA, accB);  // self term
    int rs = rowptr[n], re = rowptr[n + 1];
    int k = rs;
    for (; k + 4 <= re; k += 4) {
        int s0 = eidx[k + 0], s1 = eidx[k + 1], s2 = eidx[k + 2], s3 = eidx[k + 3];
        uint4 r0 = g4[(size_t)s0 * V + v];
        uint4 r1 = g4[(size_t)s1 * V + v];
        uint4 r2 = g4[(size_t)s2 * V + v];
        uint4 r3 = g4[(size_t)s3 * V + v];
        acc8h(r0, accA, accB);
        acc8h(r1, accA, accB);
        acc8h(r2, accA, accB);
        acc8h(r3, accA, accB);
    }
    for (; k < re; ++k) {
        acc8h(g4[(size_t)eidx[k] * V + v], accA, accB);
    }
    float dn = dis[n];
    accA.x *= dn; accA.y *= dn; accA.z *= dn; accA.w *= dn;
    accB.x *= dn; accB.y *= dn; accB.z *= dn; accB.w *= dn;
    if (HASB) {
        float4 b0 = ((const float4*)b)[v * 2 + 0];
        float4 b1 = ((const float4*)b)[v * 2 + 1];
        accA.x += b0.x; accA.y += b0.y; accA.z += b0.z; accA.w += b0.w;
        accB.x += b1.x; accB.y += b1.y; accB.z += b1.z; accB.w += b1.w;
    }
    accA.x = act_f<ACT>(accA.x); accA.y = act_f<ACT>(accA.y);
    accA.z = act_f<ACT>(accA.z); accA.w = act_f<ACT>(accA.w);
    accB.x = act_f<ACT>(accB.x); accB.y = act_f<ACT>(accB.y);
    accB.z = act_f<ACT>(accB.z); accB.w = act_f<ACT>(accB.w);
    if (OUTH) {
        uint4 u;
        u.x = pack2h(accA.x, accA.y);
        u.y = pack2h(accA.z, accA.w);
        u.z = pack2h(accB.x, accB.y);
        u.w = pack2h(accB.z, accB.w);
        ((uint4*)out)[(size_t)n * V + v] = u;
    } else {
        float4* op = (float4*)out + (size_t)n * (C / 4) + v * 2;
        op[0] = accA;
        op[1] = accB;
    }
}

template <int C, int ACT, bool HASB, bool OUTH>
__global__ void k_gatherh(const unsigned short* __restrict__ g, const int* __restrict__ rowptr,
                          const int* __restrict__ eidx, const float* __restrict__ dis,
                          const float* __restrict__ b, float* __restrict__ out) {
    static_assert(C % 4 == 0, "C%4");
    constexpr int V = C / 4;
    int t = blockIdx.x * BS + threadIdx.x;
    if (t >= NN * V) return;
    int n = t / V, v = t % V;
    const uint2* g2 = (const uint2*)g;
    float4 acc = cvt4h(g2[(size_t)n * V + v]);  // self term
    int rs = rowptr[n], re = rowptr[n + 1];
    int k = rs;
    for (; k + 4 <= re; k += 4) {
        int s0 = eidx[k + 0], s1 = eidx[k + 1], s2 = eidx[k + 2], s3 = eidx[k + 3];
        uint2 r0 = g2[(size_t)s0 * V + v];
        uint2 r1 = g2[(size_t)s1 * V + v];
        uint2 r2 = g2[(size_t)s2 * V + v];
        uint2 r3 = g2[(size_t)s3 * V + v];
        float4 h0 = cvt4h(r0), h1 = cvt4h(r1), h2 = cvt4h(r2), h3 = cvt4h(r3);
        acc.x += (h0.x + h1.x) + (h2.x + h3.x);
        acc.y += (h0.y + h1.y) + (h2.y + h3.y);
        acc.z += (h0.z + h1.z) + (h2.z + h3.z);
        acc.w += (h0.w + h1.w) + (h2.w + h3.w);
    }
    for (; k < re; ++k) {
        float4 hv = cvt4h(g2[(size_t)eidx[k] * V + v]);
        acc.x += hv.x; acc.y += hv.y; acc.z += hv.z; acc.w += hv.w;
    }
    float dn = dis[n];
    acc.x *= dn; acc.y *= dn; acc.z *= dn; acc.w *= dn;
    if (HASB) {
        float4 bb = ((const float4*)b)[v];
        acc.x += bb.x; acc.y += bb.y; acc.z += bb.z; acc.w += bb.w;
    }
    acc.x = act_f<ACT>(acc.x);
    acc.y = act_f<ACT>(acc.y);
    acc.z = act_f<ACT>(acc.z);
    acc.w = act_f<ACT>(acc.w);
    if (OUTH) {
        uint2 u;
        u.x = pack2h(acc.x, acc.y);
        u.y = pack2h(acc.z, acc.w);
        ((uint2*)out)[(size_t)n * V + v] = u;
    } else {
        ((float4*)out)[(size_t)n * V + v] = acc;
    }
}

template <int ACT, bool HASB>
__global__ void k_gather3d(const float* __restrict__ g, const int* __restrict__ rowptr,
                           const int* __restrict__ eidx, const float* __restrict__ dis,
                           const float* __restrict__ b, float* __restrict__ out) {
    int n = blockIdx.x * BS + threadIdx.x;
    if (n >= NN) return;
    const float* gp = g + (size_t)n * 3;
    float a0 = gp[0], a1 = gp[1], a2 = gp[2];
    int rs = rowptr[n], re = rowptr[n + 1];
    int k = rs;
    for (; k + 4 <= re; k += 4) {
        const float* q0 = g + (size_t)eidx[k + 0] * 3;
        const float* q1 = g + (size_t)eidx[k + 1] * 3;
        const float* q2 = g + (size_t)eidx[k + 2] * 3;
        const float* q3 = g + (size_t)eidx[k + 3] * 3;
        float b00 = q0[0], b01 = q0[1], b02 = q0[2];
        float b10 = q1[0], b11 = q1[1], b12 = q1[2];
        float b20 = q2[0], b21 = q2[1], b22 = q2[2];
        float b30 = q3[0], b31 = q3[1], b32 = q3[2];
        a0 += (b00 + b10) + (b20 + b30);
        a1 += (b01 + b11) + (b21 + b31);
        a2 += (b02 + b12) + (b22 + b32);
    }
    for (; k < re; ++k) {
        const float* gq = g + (size_t)eidx[k] * 3;
        a0 += gq[0]; a1 += gq[1]; a2 += gq[2];
    }
    float dn = dis[n];
    a0 *= dn; a1 *= dn; a2 *= dn;
    if (HASB) { a0 += b[0]; a1 += b[1]; a2 += b[2]; }
    float* op = out + (size_t)n * 3;
    op[0] = act_f<ACT>(a0);
    op[1] = act_f<ACT>(a1);
    op[2] = act_f<ACT>(a2);
}

__global__ void k_scale3(const float* __restrict__ x, const float* __restrict__ dis,
                         float* __restrict__ g) {
    int i = blockIdx.x * BS + threadIdx.x;
    if (i < NN * 3) g[i] = x[i] * dis[i / 3];
}

// ---------------- fused latent stack ----------------
__global__ __launch_bounds__(256) void k_latent(const unsigned short* __restrict__ in20,
                                                const float* __restrict__ el1_w, const float* __restrict__ el1_b,
                                                const float* __restrict__ el2_w, const float* __restrict__ el2_b,
                                                const float* __restrict__ dl1_w, const float* __restrict__ dl1_b,
                                                const float* __restrict__ dl2_w, const float* __restrict__ dl2_b,
                                                const float* __restrict__ dis,
                                                unsigned short* __restrict__ G) {
    __shared__ float w1[200], b1[10], w2[30], b2[3], w3[30], b3[10], w4[200], b4[20];
    int t = threadIdx.x;
    if (t < 200) w1[t] = el1_w[t];
    if (t < 10) b1[t] = el1_b[t];
    if (t < 30) w2[t] = el2_w[t];
    if (t < 3) b2[t] = el2_b[t];
    if (t < 30) w3[t] = dl1_w[t];
    if (t < 10) b3[t] = dl1_b[t];
    if (t < 200) w4[t] = dl2_w[t];
    if (t < 20) b4[t] = dl2_b[t];
    __syncthreads();
    int n = blockIdx.x * 256 + t;
    if (n >= NN) return;
    float h0[20];
    const uint2* ip = (const uint2*)in20 + (size_t)n * 5;
#pragma unroll
    for (int v = 0; v < 5; ++v) {
        float4 f = cvt4h(ip[v]);
        h0[v * 4 + 0] = f.x; h0[v * 4 + 1] = f.y;
        h0[v * 4 + 2] = f.z; h0[v * 4 + 3] = f.w;
    }
    float a1[10];
#pragma unroll
    for (int j = 0; j < 10; ++j) {
        float s = b1[j];
#pragma unroll
        for (int i = 0; i < 20; ++i) s = fmaf(h0[i], w1[i * 10 + j], s);
        a1[j] = fmaxf(s, 0.0f);
    }
    float a2[3];
#pragma unroll
    for (int j = 0; j < 3; ++j) {
        float s = b2[j];
#pragma unroll
        for (int i = 0; i < 10; ++i) s = fmaf(a1[i], w2[i * 3 + j], s);
        a2[j] = s;
    }
    float a3[10];
#pragma unroll
    for (int j = 0; j < 10; ++j) {
        float s = b3[j];
#pragma unroll
        for (int i = 0; i < 3; ++i) s = fmaf(a2[i], w3[i * 10 + j], s);
        a3[j] = fmaxf(s, 0.0f);
    }
    float dn = dis[n];
    uint2* gp = (uint2*)G + (size_t)n * 5;
#pragma unroll
    for (int v = 0; v < 5; ++v) {
        float o[4];
#pragma unroll
        for (int q = 0; q < 4; ++q) {
            int j = v * 4 + q;
            float s = b4[j];
#pragma unroll
            for (int i = 0; i < 10; ++i) s = fmaf(a3[i], w4[i * 20 + j], s);
            o[q] = fmaxf(s, 0.0f) * dn;
        }
        uint2 u;
        u.x = pack2h(o[0], o[1]);
        u.y = pack2h(o[2], o[3]);
        gp[v] = u;
    }
}

// ---------------- W prep: fp32 [K][N] -> fp16 fragment-swizzled, zero-padded ----------------
// wh[((k>>3)*NPAD + n)*8 + (k&7)]
template <int K, int N>
__global__ void k_wprep(const float* __restrict__ w, _Float16* __restrict__ wh) {
    constexpr int KP = (K + 31) & ~31;
    constexpr int NT = (N + 15) / 16;
    constexpr int NPAD = NT * 16;
    int i = blockIdx.x * 256 + threadIdx.x;
    if (i >= KP * NPAD) return;
    int k = i / NPAD, n = i % NPAD;
    float v = (k < K && n < N) ? w[k * N + n] : 0.0f;
    wh[((size_t)(k >> 3) * NPAD + n) * 8 + (k & 7)] = (_Float16)v;
}

// ---------------- MFMA GEMM, LDS-free: X [NN][K] fp16 -> out [NN][N] fp16 ----------------
// 4 waves/block, each owns a 16-row tile. A-frags direct global 16B loads;
// B-frags direct from pre-swizzled wh (L2-broadcast). Verified mappings:
// A/B outer idx = lane&15, k = quad*8+j; C/D col=lane&15, row=quad*4+reg.
template <int K, int N, int ACT, bool HASB, int OUTM>
__global__ __launch_bounds__(256) void k_mfma(const unsigned short* __restrict__ x,
                                              const _Float16* __restrict__ wh,
                                              const float* __restrict__ bias,
                                              unsigned short* __restrict__ out,
                                              const float* __restrict__ dis) {
    static_assert(K % 8 == 0, "K%8");
    constexpr int KP = (K + 31) & ~31;
    constexpr int KC = KP / 32;
    constexpr int NT = (N + 15) / 16;
    constexpr int NPAD = NT * 16;
    const int wid = blockIdx.x * 4 + (threadIdx.x >> 6);
    const int lane = threadIdx.x & 63;
    const int lm = lane & 15;
    const int quad = lane >> 4;
    const int arow = wid * 16 + lm;

    f32x4 acc[NT];
#pragma unroll
    for (int t = 0; t < NT; ++t) acc[t] = (f32x4){0.f, 0.f, 0.f, 0.f};

    const _Float16* xr = (const _Float16*)x + (size_t)arow * K;
#pragma unroll
    for (int kc = 0; kc < KC; ++kc) {
        int k0 = kc * 32 + quad * 8;
        half8 a = (half8)(_Float16)0;
        if (arow < NN && k0 < K) a = *(const half8*)(xr + k0);
#pragma unroll
        for (int t = 0; t < NT; ++t) {
            half8 bf = *(const half8*)&wh[((size_t)(kc * 4 + quad) * NPAD + t * 16 + lm) * 8];
            acc[t] = __builtin_amdgcn_mfma_f32_16x16x32_f16(a, bf, acc[t], 0, 0, 0);
        }
    }

    float bb[NT];
#pragma unroll
    for (int t = 0; t < NT; ++t) {
        int col = t * 16 + lm;
        bb[t] = (HASB && col < N) ? bias[col] : 0.0f;
    }
#pragma unroll
    for (int r = 0; r < 4; ++r) {
        int orow = wid * 16 + quad * 4 + r;
        if (orow < NN) {
            float dn = (OUTM == 2) ? dis[orow] : 1.0f;
#pragma unroll
            for (int t = 0; t < NT; ++t) {
                int col = t * 16 + lm;
                if (col < N) {
                    float v = act_f<ACT>(acc[t][r] + bb[t]);
                    if (OUTM == 2) v *= dn;
                    out[(size_t)orow * N + col] = h16(v);
                }
            }
        }
    }
}

// ---------------- small-CIN matmul, vectorized output (fp32 or fp16) ----------------
template <int CIN, int COUT, int ACT, int OUTM>
__global__ void k_mm_rowbcast(const float* __restrict__ x, const float* __restrict__ w,
                              const float* __restrict__ b, float* __restrict__ out) {
    static_assert(COUT % 4 == 0, "c4");
    constexpr int COUT4 = COUT / 4;
    int i = blockIdx.x * BS + threadIdx.x;
    if (i >= NN * COUT4) return;
    int n = i / COUT4, c4 = i % COUT4;
    const float4* w4 = (const float4*)w;
    float4 acc = ((const float4*)b)[c4];
    const float* xr = x + (size_t)n * CIN;
#pragma unroll
    for (int ci = 0; ci < CIN; ++ci) {
        float xv = xr[ci];
        float4 wv = w4[ci * COUT4 + c4];
        acc.x = fmaf(xv, wv.x, acc.x);
        acc.y = fmaf(xv, wv.y, acc.y);
        acc.z = fmaf(xv, wv.z, acc.z);
        acc.w = fmaf(xv, wv.w, acc.w);
    }
    acc.x = act_f<ACT>(acc.x); acc.y = act_f<ACT>(acc.y);
    acc.z = act_f<ACT>(acc.z); acc.w = act_f<ACT>(acc.w);
    if (OUTM == 3) {
        uint2 u;
        u.x = pack2h(acc.x, acc.y);
        u.y = pack2h(acc.z, acc.w);
        ((uint2*)out)[(size_t)n * COUT4 + c4] = u;
    } else {
        ((float4*)out)[(size_t)n * COUT4 + c4] = acc;
    }
}

// ---------------- mm_vec4: TM=8 rows x 4 cols per thread (INH: fp16 input) ----------------
template <int CIN, int COUT, int ACT, bool HASB, int OUTM, bool INH>
__global__ void k_mm_vec4(const float* __restrict__ x, const float* __restrict__ w,
                          const float* __restrict__ b, float* __restrict__ out,
                          const float* __restrict__ dis) {
    static_assert(CIN % 4 == 0 && COUT % 4 == 0, "align");
    constexpr int TM = 8;
    constexpr int CIN4 = CIN / 4;
    constexpr int COUT4 = COUT / 4;
    constexpr int RG = NN / TM;
    int i = blockIdx.x * BS + threadIdx.x;
    if (i >= RG * COUT4) return;
    int c4 = i % COUT4;
    int n0 = (i / COUT4) * TM;
    const float4* x4 = (const float4*)x;
    const uint2* xh = (const uint2*)x;
    const float4* w4 = (const float4*)w;
    float4 acc[TM];
    float4 bb = HASB ? ((const float4*)b)[c4] : make_float4(0.f, 0.f, 0.f, 0.f);
#pragma unroll
    for (int r = 0; r < TM; ++r) acc[r] = bb;
    for (int k4 = 0; k4 < CIN4; ++k4) {
        float4 wv[4];
#pragma unroll
        for (int j = 0; j < 4; ++j) wv[j] = w4[(size_t)(4 * k4 + j) * COUT4 + c4];
#pragma unroll
        for (int r = 0; r < TM; ++r) {
            float4 xv;
            if (INH) xv = cvt4h(xh[(size_t)(n0 + r) * CIN4 + k4]);
            else xv = x4[(size_t)(n0 + r) * CIN4 + k4];
            acc[r].x = fmaf(xv.x, wv[0].x, fmaf(xv.y, wv[1].x, fmaf(xv.z, wv[2].x, fmaf(xv.w, wv[3].x, acc[r].x))));
            acc[r].y = fmaf(xv.x, wv[0].y, fmaf(xv.y, wv[1].y, fmaf(xv.z, wv[2].y, fmaf(xv.w, wv[3].y, acc[r].y))));
            acc[r].z = fmaf(xv.x, wv[0].z, fmaf(xv.y, wv[1].z, fmaf(xv.z, wv[2].z, fmaf(xv.w, wv[3].z, acc[r].z))));
            acc[r].w = fmaf(xv.x, wv[0].w, fmaf(xv.y, wv[1].w, fmaf(xv.z, wv[2].w, fmaf(xv.w, wv[3].w, acc[r].w))));
        }
    }
#pragma unroll
    for (int r = 0; r < TM; ++r) {
        float vx = act_f<ACT>(acc[r].x), vy = act_f<ACT>(acc[r].y);
        float vz = act_f<ACT>(acc[r].z), vw = act_f<ACT>(acc[r].w);
        size_t gi = (size_t)(n0 + r) * COUT4 + c4;
        if (OUTM == 2) {
            float dn = dis[n0 + r];
            uint2 u;
            u.x = pack2h(vx * dn, vy * dn);
            u.y = pack2h(vz * dn, vw * dn);
            ((uint2*)out)[gi] = u;
        } else if (OUTM == 1) {
            float dn = dis[n0 + r];
            ((float4*)out)[gi] = make_float4(vx * dn, vy * dn, vz * dn, vw * dn);
        } else {
            ((float4*)out)[gi] = make_float4(vx, vy, vz, vw);
        }
    }
}

// ---------------- vec matmul (odd COUT; INH = fp16 input) ----------------
template <int CIN, int COUT, int ACT, bool HASB, int OUTM, bool INH>
__global__ void k_mm_vec(const float* __restrict__ x, const float* __restrict__ w,
                         const float* __restrict__ b, float* __restrict__ out,
                         const float* __restrict__ dis) {
    static_assert(CIN % 4 == 0, "CIN%4");
    constexpr int TM = 8;
    constexpr int CIN4 = CIN / 4;
    constexpr int RG = NN / TM;
    int i = blockIdx.x * BS + threadIdx.x;
    if (i >= RG * COUT) return;
    int c = i % COUT;
    int n0 = (i / COUT) * TM;
    float acc[TM];
    float bb = HASB ? b[c] : 0.0f;
#pragma unroll
    for (int r = 0; r < TM; ++r) acc[r] = bb;
    const float4* x4 = (const float4*)x;
    const uint2* xh = (const uint2*)x;
    for (int k = 0; k < CIN4; ++k) {
        float w0 = w[(4 * k + 0) * COUT + c];
        float w1 = w[(4 * k + 1) * COUT + c];
        float w2 = w[(4 * k + 2) * COUT + c];
        float w3 = w[(4 * k + 3) * COUT + c];
#pragma unroll
        for (int r = 0; r < TM; ++r) {
            float4 xv;
            if (INH) xv = cvt4h(xh[(size_t)(n0 + r) * CIN4 + k]);
            else xv = x4[(size_t)(n0 + r) * CIN4 + k];
            acc[r] = fmaf(xv.x, w0, fmaf(xv.y, w1, fmaf(xv.z, w2, fmaf(xv.w, w3, acc[r]))));
        }
    }
#pragma unroll
    for (int r = 0; r < TM; ++r) {
        int row = n0 + r;
        float dn = (OUTM == 1 || OUTM == 2) ? dis[row] : 0.0f;
        store1<OUTM>(out, (size_t)row * COUT + c, act_f<ACT>(acc[r]), dn);
    }
}

extern "C" void kernel_launch(void* const* d_in, const int* in_sizes, int n_in,
                              void* d_out, int out_size, void* d_ws, size_t ws_size,
                              hipStream_t stream) {
    const float* x = (const float*)d_in[0];
    const int* ei = (const int*)d_in[1];
    const int* src = ei;
    const int* dst = ei + EE;
    const float* eg1_w = (const float*)d_in[2];  const float* eg1_b = (const float*)d_in[3];
    const float* eg2_w = (const float*)d_in[4];  const float* eg2_b = (const float*)d_in[5];
    const float* eg3_w = (const float*)d_in[6];  const float* eg3_b = (const float*)d_in[7];
    const float* eg4_w = (const float*)d_in[8];  const float* eg4_b = (const float*)d_in[9];
    const float* el1_w = (const float*)d_in[10]; const float* el1_b = (const float*)d_in[11];
    const float* el2_w = (const float*)d_in[12]; const float* el2_b = (const float*)d_in[13];
    const float* dl1_w = (const float*)d_in[14]; const float* dl1_b = (const float*)d_in[15];
    const float* dl2_w = (const float*)d_in[16]; const float* dl2_b = (const float*)d_in[17];
    const float* dg1_w = (const float*)d_in[18]; const float* dg1_b = (const float*)d_in[19];
    const float* dg2_w = (const float*)d_in[20]; const float* dg2_b = (const float*)d_in[21];
    const float* dg3_w = (const float*)d_in[22]; const float* dg3_b = (const float*)d_in[23];
    const float* dg4_w = (const float*)d_in[24]; const float* dg4_b = (const float*)d_in[25];
    float* out = (float*)d_out;

    char* ws = (char*)d_ws;
    size_t off = 0;
    auto alloc = [&](size_t bytes) {
        void* p = ws + off;
        off += (bytes + 15) & ~(size_t)15;
        return p;
    };
    int* part_cnt = (int*)alloc(sizeof(int) * NP_);
    int* scan_out = (int*)alloc(sizeof(int) * NP_);
    int* bsums    = (int*)alloc(sizeof(int) * NPB);
    int* bbase    = (int*)alloc(sizeof(int) * (NBUCKET + 1));
    int* rowptr   = (int*)alloc(sizeof(int) * (NN + 1));
    float* dis    = (float*)alloc(sizeof(float) * NN);
    int* eidx     = (int*)alloc(sizeof(int) * EE);
    unsigned* epb = (unsigned*)alloc(sizeof(unsigned) * EE);
    unsigned short* G = (unsigned short*)alloc(sizeof(unsigned short) * 80 * (size_t)NN);
    float* bufA = (float*)alloc(sizeof(float) * 160 * (size_t)NN);
    float* bufB = (float*)alloc(sizeof(float) * 160 * (size_t)NN);
    // swizzled fp16 weights: sizes (KP/8)*NPAD*8 halves
    _Float16* whEg2 = (_Float16*)alloc(sizeof(_Float16) * (160 / 8) * 80 * 8);   // K=160,N=80
    _Float16* whEg3 = (_Float16*)alloc(sizeof(_Float16) * (96 / 8) * 48 * 8);    // K=80,N=40
    _Float16* whDg2 = (_Float16*)alloc(sizeof(_Float16) * (64 / 8) * 80 * 8);    // K=40,N=80
    _Float16* whDg3 = (_Float16*)alloc(sizeof(_Float16) * (96 / 8) * 160 * 8);   // K=80,N=160

    // ---- CSR build (no global atomics anywhere) ----
    k_hist<<<NB_PART, 256, 0, stream>>>(dst, part_cnt);
    k_scanA<<<NPB, BS, 0, stream>>>(part_cnt, scan_out, bsums);
    k_scanB<<<1, 64, 0, stream>>>(bsums);
    k_scanC<<<cdiv(NP_, BS), BS, 0, stream>>>(scan_out, bsums, bbase);
    k_part<<<NB_PART, 256, 0, stream>>>(src, dst, scan_out, epb);
    k_fine2<<<NBUCKET, 256, 0, stream>>>(bbase, epb, eidx, rowptr, dis);

    // ---- W prep (tiny, one-time) ----
    k_wprep<160, 80><<<cdiv(160 * 80, 256), 256, 0, stream>>>(eg2_w, whEg2);
    k_wprep<80, 40><<<cdiv(96 * 48, 256), 256, 0, stream>>>(eg3_w, whEg3);
    k_wprep<40, 80><<<cdiv(64 * 80, 256), 256, 0, stream>>>(dg2_w, whDg2);
    k_wprep<80, 160><<<cdiv(96 * 160, 256), 256, 0, stream>>>(dg3_w, whDg3);

    // ---- eg1 (3->160): AGG-first; output fp16 (plain, row-major) into bufB ----
    k_scale3<<<cdiv(3LL * NN, BS), BS, 0, stream>>>(x, dis, bufB);
    k_gather3d<0, false><<<cdiv(NN, BS), BS, 0, stream>>>(bufB, rowptr, eidx, dis, nullptr, bufA);
    k_mm_rowbcast<3, 160, 1, 3><<<cdiv(NN * 40LL, BS), BS, 0, stream>>>(bufA, eg1_w, eg1_b, bufB);

    // ---- eg2 (160->80): MFMA (LDS-free) -> fp16*dis G; wide gather -> fp16 out ----
    k_mfma<160, 80, 0, false, 2><<<cdiv(NN, 64), 256, 0, stream>>>(
        (const unsigned short*)bufB, whEg2, nullptr, G, dis);
    k_gatherw<80, 1, true, true><<<cdiv(NN * 10LL, BS), BS, 0, stream>>>(G, rowptr, eidx, dis, eg2_b, bufA);

    // ---- eg3 (80->40): MFMA -> fp16*dis G; wide gather -> fp16 out ----
    k_mfma<80, 40, 0, false, 2><<<cdiv(NN, 64), 256, 0, stream>>>(
        (const unsigned short*)bufA, whEg3, nullptr, G, dis);
    k_gatherw<40, 1, true, true><<<cdiv(NN * 5LL, BS), BS, 0, stream>>>(G, rowptr, eidx, dis, eg3_b, bufB);

    // ---- eg4 (40->20): mm (fp16 in) -> fp16*dis G; gather -> fp16 out ----
    k_mm_vec4<40, 20, 0, false, 2, true><<<cdiv((NN / 8) * 5LL, BS), BS, 0, stream>>>(
        bufB, eg4_w, nullptr, (float*)G, dis);
    k_gatherh<20, 1, true, true><<<cdiv(NN * 5LL, BS), BS, 0, stream>>>(G, rowptr, eidx, dis, eg4_b, bufA);

    // ---- fused latent stack (20->10->3->10->20), writes dis-scaled fp16 G for dg1 ----
    k_latent<<<cdiv(NN, 256), 256, 0, stream>>>((const unsigned short*)bufA,
        el1_w, el1_b, el2_w, el2_b, dl1_w, dl1_b, dl2_w, dl2_b, dis, G);

    // ---- dg1 (20->40): gather -> fp16, mm (fp16 in) -> fp16*dis G ----
    k_gatherh<20, 0, false, true><<<cdiv(NN * 5LL, BS), BS, 0, stream>>>(G, rowptr, eidx, dis, nullptr, bufA);
    k_mm_vec4<20, 40, 1, true, 2, true><<<cdiv((NN / 8) * 10LL, BS), BS, 0, stream>>>(
        bufA, dg1_w, dg1_b, (float*)G, dis);

    // ---- dg2 (40->80): wide gather -> fp16, MFMA (relu+bias) -> fp16*dis G ----
    k_gatherw<40, 0, false, true><<<cdiv(NN * 5LL, BS), BS, 0, stream>>>(G, rowptr, eidx, dis, nullptr, bufB);
    k_mfma<40, 80, 1, true, 2><<<cdiv(NN, 64), 256, 0, stream>>>(
        (const unsigned short*)bufB, whDg2, dg2_b, G, dis);

    // ---- dg3 (80->160): wide gather -> fp16, MFMA (relu+bias) -> fp16 plain ----
    k_gatherw<80, 0, false, true><<<cdiv(NN * 10LL, BS), BS, 0, stream>>>(G, rowptr, eidx, dis, nullptr, bufA);
    k_mfma<80, 160, 1, true, 3><<<cdiv(NN, 64), 256, 0, stream>>>(
        (const unsigned short*)bufA, whDg3, dg3_b, (unsigned short*)bufB, nullptr);

    // ---- dg4 (160->3): mm (fp16 in) writes dis-scaled fp32 g; tanh in gather ----
    k_mm_vec<160, 3, 0, false, 1, true><<<cdiv((NN / 8) * 3LL, BS), BS, 0, stream>>>(bufB, dg4_w, nullptr, bufA, dis);
    k_gather3d<2, true><<<cdiv(NN, BS), BS, 0, stream>>>(bufA, rowptr, eidx, dis, dg4_b, out);
}